// Round 1
// baseline (75.928 us; speedup 1.0000x reference)
//
#include <hip/hip_runtime.h>

#define NROWS 16384
#define DDIM  256
#define K1BLK 512                 // 2 blocks/CU, 8 waves/CU; 32 rows/block
#define K1ROWS (NROWS / K1BLK)    // 32
#define K3BLK 2048

// g = (X W)(X^T (X b)) via u = Xb, v = X^T u, w2 = W v, g = X w2.
// R8 restructure: NO atomics. k1 blocks each own a unique partial-v row
// (plain stores, fully written -> no memset / poison-tolerance needed).
// Theory: 524K device-scope atomicAdds into 64KB were serializing at the
// memory-side coherence point (~tens of µs); unique partials hit the
// streaming floor instead.

// ---------------------------------------------------------------------------
// k1: per-row t = x.b (6-step butterfly), vacc += t*x. 32 rows/block
// (8 rows/wave, unrolled -> 8 independent row loads in flight/thread).
// Block LDS-combines the 4 wave partials, stores partials[bid][0..255].
// ---------------------------------------------------------------------------
__global__ __launch_bounds__(256) void k1_v(const float* __restrict__ X,
                                            const float* __restrict__ b,
                                            float* __restrict__ partials) {
    const int tid  = threadIdx.x;
    const int lane = tid & 63;
    const int wave = tid >> 6;
    const int bid  = blockIdx.x;

    const float4* X4 = (const float4*)X;
    const float4  bf = ((const float4*)b)[lane];

    float4 vacc = make_float4(0.f, 0.f, 0.f, 0.f);
    const int row0 = bid * K1ROWS + wave * (K1ROWS / 4);
    #pragma unroll
    for (int i = 0; i < K1ROWS / 4; ++i) {
        const float4 xv = X4[(row0 + i) * 64 + lane];
        float t = xv.x * bf.x + xv.y * bf.y + xv.z * bf.z + xv.w * bf.w;
        #pragma unroll
        for (int off = 32; off; off >>= 1) t += __shfl_xor(t, off, 64);
        vacc.x += t * xv.x; vacc.y += t * xv.y;
        vacc.z += t * xv.z; vacc.w += t * xv.w;
    }

    __shared__ float sp[4][DDIM];
    ((float4*)sp[wave])[lane] = vacc;
    __syncthreads();
    // unique destination per block -- coalesced plain store, no atomic
    partials[bid * DDIM + tid] = sp[0][tid] + sp[1][tid] + sp[2][tid] + sp[3][tid];
}

// ---------------------------------------------------------------------------
// k2: 64 blocks. Each block reduces all 512 partial rows (512 KB, L2/L3
// resident after k1's flush): thread (wave,lane) sums 128 rows of float4
// col-group lane (coalesced), LDS-combine -> v; then ONE butterfly row-dot
// per wave: w2[bid*4+wave].
// ---------------------------------------------------------------------------
__global__ __launch_bounds__(256) void k2_w2(const float* __restrict__ partials,
                                             const float* __restrict__ W,
                                             float* __restrict__ w2) {
    const int tid  = threadIdx.x;
    const int lane = tid & 63;   // float4 column group
    const int wave = tid >> 6;   // partial-row segment

    const float4* P4 = (const float4*)partials;
    float4 acc = make_float4(0.f, 0.f, 0.f, 0.f);
    const int r0 = wave * (K1BLK / 4);
    #pragma unroll 8
    for (int j = 0; j < K1BLK / 4; ++j) {
        const float4 p = P4[(r0 + j) * 64 + lane];
        acc.x += p.x; acc.y += p.y; acc.z += p.z; acc.w += p.w;
    }

    __shared__ float4 sp4[4][64];
    sp4[wave][lane] = acc;
    __syncthreads();

    const float* spf = (const float*)sp4;  // spf[seg*256 + col]
    __shared__ __align__(16) float sv[DDIM];
    sv[tid] = spf[tid] + spf[256 + tid] + spf[512 + tid] + spf[768 + tid];
    __syncthreads();

    const float4 vf = ((const float4*)sv)[lane];
    const int row = blockIdx.x * 4 + wave;
    const float4 w = ((const float4*)W)[row * 64 + lane];
    float t = w.x * vf.x + w.y * vf.y + w.z * vf.z + w.w * vf.w;
    #pragma unroll
    for (int off = 32; off; off >>= 1) t += __shfl_xor(t, off, 64);
    if (lane == 0) w2[row] = t;
}

// ---------------------------------------------------------------------------
// k3: g = X w2. 2048 blocks, 2 rows/wave. X is L3-warm from k1.
// ---------------------------------------------------------------------------
__global__ __launch_bounds__(256) void k3_g(const float* __restrict__ X,
                                            const float* __restrict__ w2,
                                            float* __restrict__ g) {
    const int tid  = threadIdx.x;
    const int lane = tid & 63;
    const int wave = tid >> 6;

    const float4* X4 = (const float4*)X;
    const float4  wf = ((const float4*)w2)[lane];

    const int row0 = blockIdx.x * 8 + wave * 2;
    #pragma unroll
    for (int i = 0; i < 2; ++i) {
        const float4 xv = X4[(row0 + i) * 64 + lane];
        float t = xv.x * wf.x + xv.y * wf.y + xv.z * wf.z + xv.w * wf.w;
        #pragma unroll
        for (int off = 32; off; off >>= 1) t += __shfl_xor(t, off, 64);
        if (lane == 0) g[row0 + i] = t;
    }
}

extern "C" void kernel_launch(void* const* d_in, const int* in_sizes, int n_in,
                              void* d_out, int out_size, void* d_ws, size_t ws_size,
                              hipStream_t stream) {
    const float* X = (const float*)d_in[0];   // (16384, 256)
    const float* W = (const float*)d_in[1];   // (256, 256)
    const float* b = (const float*)d_in[2];   // (256,)
    float* out = (float*)d_out;               // (16384,)

    float* partials = (float*)d_ws;             // 512 * 256 floats, fully written
    float* w2       = partials + K1BLK * DDIM;  // 256 floats

    k1_v <<<K1BLK, 256, 0, stream>>>(X, b, partials);
    k2_w2<<<64,    256, 0, stream>>>(partials, W, w2);
    k3_g <<<K3BLK, 256, 0, stream>>>(X, w2, out);
}